// Round 9
// baseline (337.303 us; speedup 1.0000x reference)
//
#include <hip/hip_runtime.h>
#include <math.h>

#define N_NODES    100000
#define N_EDGES    3200000
#define N_FEAT     128
#define N_CLASSES  16
#define NUM_GRAPHS 512
#define NB         782          // bins of 128 nodes: bin = dst>>7
#define NBLK_A     1024         // blocks in binning passes
#define EPB        3125         // edges per block: 1024*3125 = 3.2M exactly

typedef unsigned short ushort_t;

__device__ __forceinline__ float bf2f(ushort_t u) {
    return __uint_as_float(((unsigned)u) << 16);
}
__device__ __forceinline__ ushort_t f2bf(float f) {   // RNE
    unsigned u = __float_as_uint(f);
    unsigned r = (u >> 16) & 1;
    return (ushort_t)((u + 0x7FFFu + r) >> 16);
}

// ---------- pass A0: per-block coarse histogram ----------

__global__ void binhist_kernel(const int* __restrict__ dst, int* __restrict__ hist) {
    __shared__ int h[NB];
    int t = threadIdx.x;
    for (int i = t; i < NB; i += 256) h[i] = 0;
    __syncthreads();
    int base = blockIdx.x * EPB;
    for (int e = base + t; e < base + EPB; e += 256) atomicAdd(&h[dst[e] >> 7], 1);
    __syncthreads();
    for (int i = t; i < NB; i += 256) hist[blockIdx.x * NB + i] = h[i];
}

// ---------- generic 32x32 LDS transpose: in[R][C] -> out[C][R] ----------

__global__ void transpose_kernel(const int* __restrict__ in, int* __restrict__ out,
                                 int R, int C) {
    __shared__ int tile[32][33];
    int tx = threadIdx.x & 31, ty = threadIdx.x >> 5;   // 1024 threads
    int c0 = blockIdx.x * 32, r0 = blockIdx.y * 32;
    int ic = c0 + tx, ir = r0 + ty;
    tile[ty][tx] = (ir < R && ic < C) ? in[ir * C + ic] : 0;
    __syncthreads();
    int oc = r0 + tx, orr = c0 + ty;
    if (orr < C && oc < R) out[orr * R + oc] = tile[tx][ty];
}

// ---------- per-bin scan over blocks (coalesced via histT) ----------

__global__ void offs_scan_kernel(const int* __restrict__ histT, int* __restrict__ offs,
                                 int* __restrict__ total) {
    __shared__ int v[1024];
    int b = blockIdx.x, t = threadIdx.x;   // 1024 threads
    int x = histT[b * NBLK_A + t];
    v[t] = x;
    __syncthreads();
    for (int off = 1; off < 1024; off <<= 1) {
        int a = (t >= off) ? v[t - off] : 0;
        __syncthreads();
        v[t] += a;
        __syncthreads();
    }
    offs[b * NBLK_A + t] = v[t] - x;
    if (t == 1023) total[b] = v[1023];
}

// ---------- scan of bin totals -> binbase ----------

__global__ void total_scan_kernel(const int* __restrict__ total, int* __restrict__ binbase) {
    __shared__ int v[1024];
    int t = threadIdx.x;
    int x = (t < NB) ? total[t] : 0;
    v[t] = x;
    __syncthreads();
    for (int off = 1; off < 1024; off <<= 1) {
        int a = (t >= off) ? v[t - off] : 0;
        __syncthreads();
        v[t] += a;
        __syncthreads();
    }
    if (t < NB) binbase[t] = v[t] - x;
}

// ---------- pass A1: local counting sort by bin, coalesced scatter ----------

__global__ void binscatter_kernel(const int* __restrict__ src, const int* __restrict__ dst,
                                  const int* __restrict__ hist, const int* __restrict__ offsT,
                                  const int* __restrict__ binbase,
                                  unsigned int* __restrict__ bins) {
    __shared__ int h[NB];                    // counts -> cursor
    __shared__ int lstart[NB];
    __shared__ int gstart[NB];
    __shared__ int sv[256];
    __shared__ unsigned int outp[EPB];       // 12.5 KB
    __shared__ unsigned short binof[EPB];    // 6.25 KB
    int t = threadIdx.x, blk = blockIdx.x;
    for (int i = t; i < NB; i += 256) h[i] = hist[blk * NB + i];
    __syncthreads();
    int b0 = 4 * t;
    int l0 = (b0 + 0 < NB) ? h[b0 + 0] : 0;
    int l1 = (b0 + 1 < NB) ? h[b0 + 1] : 0;
    int l2 = (b0 + 2 < NB) ? h[b0 + 2] : 0;
    int l3 = (b0 + 3 < NB) ? h[b0 + 3] : 0;
    int tsum = l0 + l1 + l2 + l3;
    sv[t] = tsum;
    __syncthreads();
    for (int off = 1; off < 256; off <<= 1) {
        int a = (t >= off) ? sv[t - off] : 0;
        __syncthreads();
        sv[t] += a;
        __syncthreads();
    }
    int ex = sv[t] - tsum;
    if (b0 + 0 < NB) lstart[b0 + 0] = ex;
    if (b0 + 1 < NB) lstart[b0 + 1] = ex + l0;
    if (b0 + 2 < NB) lstart[b0 + 2] = ex + l0 + l1;
    if (b0 + 3 < NB) lstart[b0 + 3] = ex + l0 + l1 + l2;
    __syncthreads();
    for (int i = t; i < NB; i += 256) {
        gstart[i] = offsT[blk * NB + i] + binbase[i];   // coalesced
        h[i] = lstart[i];                               // cursor
    }
    __syncthreads();
    int base = blk * EPB;
    for (int e = base + t; e < base + EPB; e += 256) {
        int s = src[e], d = dst[e];
        int b = d >> 7;
        int pos = atomicAdd(&h[b], 1);
        outp[pos] = (unsigned int)s | ((unsigned int)(d & 127) << 17);
        binof[pos] = (unsigned short)b;
    }
    __syncthreads();
    for (int i = t; i < EPB; i += 256) {
        int b = binof[i];
        bins[gstart[b] + (i - lstart[b])] = outp[i];
    }
}

// ---------- per-bin counting sort -> CSR, fused deg/dinv/rowp ----------

__global__ void binsort_kernel(const unsigned int* __restrict__ bins,
                               const int* __restrict__ binbase, const int* __restrict__ total,
                               int* __restrict__ csr, int* __restrict__ rowp,
                               float* __restrict__ dinv) {
    __shared__ int h[128], sv[128], cur[128];
    __shared__ int outs[5120];   // 20 KB; bin cnt ~4092 +- 64
    int b = blockIdx.x, t = threadIdx.x;
    if (t < 128) h[t] = 0;
    __syncthreads();
    int base = binbase[b], cnt = total[b];
    for (int i = t; i < cnt; i += 256) atomicAdd(&h[(bins[base + i] >> 17) & 127], 1);
    __syncthreads();
    if (t < 128) sv[t] = h[t];
    __syncthreads();
    for (int off = 1; off < 128; off <<= 1) {
        int a = 0;
        if (t < 128 && t >= off) a = sv[t - off];
        __syncthreads();
        if (t < 128) sv[t] += a;
        __syncthreads();
    }
    if (t < 128) {
        cur[t] = sv[t] - h[t];
        int node = b * 128 + t;
        if (node <= N_NODES) rowp[node] = base + sv[t] - h[t];
        if (node < N_NODES) dinv[node] = rsqrtf((float)(h[t] + 1));
    }
    __syncthreads();
    for (int i = t; i < cnt; i += 256) {
        unsigned int p = bins[base + i];
        int pos = atomicAdd(&cur[(p >> 17) & 127], 1);
        outs[pos] = (int)(p & 0x1FFFF);
    }
    __syncthreads();
    for (int i = t; i < cnt; i += 256) csr[base + i] = outs[i];
}

__global__ void row_end_kernel(int* __restrict__ rowp) {
    rowp[N_NODES] = N_EDGES;   // safety (binsort also writes it)
}

// ---------- z0 = dinv * (x @ W), bf16 out ----------

__global__ void xw_kernel(const float* __restrict__ x, const float* __restrict__ W,
                          const float* __restrict__ dinv, ushort_t* __restrict__ z) {
    __shared__ __align__(16) float sW[N_FEAT * N_CLASSES];   // 8 KB
    __shared__ __align__(16) float sx[16][132];
    int t = threadIdx.x;
    for (int i = t; i < (N_FEAT * N_CLASSES) / 4; i += 256)
        *(float4*)&sW[i * 4] = *(const float4*)&W[i * 4];
    int row0 = blockIdx.x * 16;
    for (int i = t; i < 16 * 32; i += 256) {
        int r = i >> 5, q = i & 31;
        int rr = row0 + r;
        float4 v = make_float4(0.f, 0.f, 0.f, 0.f);
        if (rr < N_NODES) v = *(const float4*)&x[(long long)rr * N_FEAT + q * 4];
        *(float4*)&sx[r][q * 4] = v;
    }
    __syncthreads();
    int r = t >> 4, c = t & 15;
    float acc = 0.0f;
#pragma unroll 8
    for (int k = 0; k < N_FEAT; ++k) acc += sx[r][k] * sW[k * N_CLASSES + c];
    int rr = row0 + r;
    if (rr < N_NODES) z[rr * N_CLASSES + c] = f2bf(dinv[rr] * acc);
}

// ---------- wave-per-node gather hop (bf16 Z), 4 edge-slots x 16 ch ----------
// z'[n] = dn^2 * (sum z[s] + z[n]); last hop: dn^1

__global__ void hop_kernel(const int* __restrict__ row, const int* __restrict__ csr,
                           const float* __restrict__ dinv,
                           const ushort_t* __restrict__ Z, ushort_t* __restrict__ O, int last) {
    int w = threadIdx.x >> 6;
    int n = blockIdx.x * 4 + w;
    if (n >= N_NODES) return;
    int l = threadIdx.x & 63;
    int c = l & 15, e = l >> 4;
    int beg = row[n], end = row[n + 1];
    float acc = 0.0f;
    int j = beg + e;
    for (; j + 4 < end; j += 8) {
        int s0 = csr[j];
        int s1 = csr[j + 4];
        float a0 = bf2f(Z[s0 * N_CLASSES + c]);
        float a1 = bf2f(Z[s1 * N_CLASSES + c]);
        acc += a0 + a1;
    }
    if (j < end) acc += bf2f(Z[csr[j] * N_CLASSES + c]);
    acc += __shfl_xor(acc, 16, 64);
    acc += __shfl_xor(acc, 32, 64);
    if (l < 16) {
        float dn = dinv[n];
        float scale = last ? dn : dn * dn;
        O[n * N_CLASSES + c] = f2bf(scale * (acc + bf2f(Z[n * N_CLASSES + c])));
    }
}

// ---------- fused pool + bias + log_softmax ----------

__device__ __forceinline__ int lower_bound(const int* __restrict__ a, int n, int key) {
    int lo = 0, hi = n;
    while (lo < hi) {
        int m = (lo + hi) >> 1;
        if (a[m] < key) lo = m + 1; else hi = m;
    }
    return lo;
}

__global__ void pool_lsm_kernel(const ushort_t* __restrict__ y, const int* __restrict__ batch,
                                const float* __restrict__ b, float* __restrict__ out) {
    int g = blockIdx.x;
    int beg = lower_bound(batch, N_NODES, g);
    int end = lower_bound(batch, N_NODES, g + 1);
    int t = threadIdx.x;
    int slot = t >> 4, c = t & 15;
    float acc = 0.0f;
    for (int n = beg + slot; n < end; n += 16) acc += bf2f(y[n * N_CLASSES + c]);
    __shared__ float red[16][16];
    red[slot][c] = acc;
    __syncthreads();
    for (int s = 8; s >= 1; s >>= 1) {
        if (slot < s) red[slot][c] += red[slot + s][c];
        __syncthreads();
    }
    if (t < 16) {
        int cnt = end - beg;
        float v = (cnt > 0) ? red[0][t] / (float)cnt + b[t] : 0.0f;
        float m = v;
        for (int mask = 1; mask < 16; mask <<= 1) m = fmaxf(m, __shfl_xor(m, mask, 64));
        float s2 = expf(v - m);
        for (int mask = 1; mask < 16; mask <<= 1) s2 += __shfl_xor(s2, mask, 64);
        out[g * N_CLASSES + t] = v - m - logf(s2);
    }
}

extern "C" void kernel_launch(void* const* d_in, const int* in_sizes, int n_in,
                              void* d_out, int out_size, void* d_ws, size_t ws_size,
                              hipStream_t stream) {
    const float* x     = (const float*)d_in[0];
    const float* W     = (const float*)d_in[1];
    const float* b     = (const float*)d_in[2];
    const int*   ei    = (const int*)d_in[3];
    const int*   batch = (const int*)d_in[4];
    float*       out   = (float*)d_out;

    const int* src = ei;
    const int* dst = ei + N_EDGES;

    char* ws = (char*)d_ws;
    int*   hist    = (int*)(ws + 0x000000);    // 1024*782*4
    int*   histT   = (int*)(ws + 0x30E000);
    int*   offs    = (int*)(ws + 0x61C000);
    int*   offsT   = (int*)(ws + 0x92A000);
    int*   total   = (int*)(ws + 0xC38000);
    int*   binbase = (int*)(ws + 0xC39000);
    float* dinv    = (float*)(ws + 0xC3A000);  // 400 KB
    int*   rowp    = (int*)(ws + 0xC9C000);    // 400 KB + 4
    unsigned int* bins = (unsigned int*)(ws + 0xCFE000);  // 12.8 MB
    int*   csr     = (int*)(ws + 0x1933000);   // 12.8 MB
    ushort_t* zA   = (ushort_t*)(ws + 0x2568000); // 3.2 MB
    ushort_t* zB   = (ushort_t*)(ws + 0x2878000); // 3.2 MB (ends ~45.6 MB)

    binhist_kernel<<<NBLK_A, 256, 0, stream>>>(dst, hist);
    {   // hist[1024][782] -> histT[782][1024]
        dim3 g1((NB + 31) / 32, NBLK_A / 32);
        transpose_kernel<<<g1, 1024, 0, stream>>>(hist, histT, NBLK_A, NB);
    }
    offs_scan_kernel<<<NB, 1024, 0, stream>>>(histT, offs, total);
    {   // offs[782][1024] -> offsT[1024][782]
        dim3 g2(NBLK_A / 32, (NB + 31) / 32);
        transpose_kernel<<<g2, 1024, 0, stream>>>(offs, offsT, NB, NBLK_A);
    }
    total_scan_kernel<<<1, 1024, 0, stream>>>(total, binbase);
    binscatter_kernel<<<NBLK_A, 256, 0, stream>>>(src, dst, hist, offsT, binbase, bins);
    binsort_kernel<<<NB, 256, 0, stream>>>(bins, binbase, total, csr, rowp, dinv);
    row_end_kernel<<<1, 1, 0, stream>>>(rowp);

    xw_kernel<<<(N_NODES + 15) / 16, 256, 0, stream>>>(x, W, dinv, zA);

    hop_kernel<<<(N_NODES + 3) / 4, 256, 0, stream>>>(rowp, csr, dinv, zA, zB, 0);
    hop_kernel<<<(N_NODES + 3) / 4, 256, 0, stream>>>(rowp, csr, dinv, zB, zA, 0);
    hop_kernel<<<(N_NODES + 3) / 4, 256, 0, stream>>>(rowp, csr, dinv, zA, zB, 1);

    pool_lsm_kernel<<<NUM_GRAPHS, 256, 0, stream>>>(zB, batch, b, out);
}